// Round 9
// baseline (838.728 us; speedup 1.0000x reference)
//
#include <hip/hip_runtime.h>
#include <hip/hip_bf16.h>

// GraphConvNet: x:[8,2048,32] f32, A0/A1/A2:[8,2048,2048] f32 row-normalized,
// W:[64,224], b/gamma/beta:[64].
// nconv: out[n,w,l] = sum_v A[n,v,w] * x[n,v,l]
// feat = concat([x, x1_0, x2_0, x1_1, x2_1, x1_2, x2_2])  (224 ch)
// h = feat @ W^T + b ; BN over (n,v) per channel; out f32 [8,2048,64]
//
// Single persistent kernel, 3 chains. Per chain:
//   Phase A: stream A once (LDS ring), hop1 MFMA, RETAIN bf16 B-fragments
//            (bfr[16] = 64 VGPR/lane). Grid barrier (512 blocks = 2/CU).
//   Phase B: stream x1 (2 MB, L2-hot), hop2 MFMA vs retained fragments.
// A is read exactly once per chain: 402 MB total instead of 804 MB.

#define V    2048
#define NB   8
#define CIN  32
#define COUT 64
#define CTOT 224

typedef __attribute__((ext_vector_type(8))) short bf16x8;
typedef __attribute__((ext_vector_type(16))) float f32x16;

static __device__ __forceinline__ short f2bf(float f) {
  __hip_bfloat16 h = __float2bfloat16(f);  // RNE
  return *reinterpret_cast<short*>(&h);
}

static __device__ __forceinline__ void gll16(const float* g, float* l) {
  // async global->LDS, 16B/lane; LDS dst = wave-uniform base + lane*16
  __builtin_amdgcn_global_load_lds(
      (const __attribute__((address_space(1))) void*)g,
      (__attribute__((address_space(3))) void*)l, 16, 0, 0);
}

// ---------------------------------------------------------------------------
// Block: (n, 32-col w-strip); 8 waves, wave wq owns v in [wq*256, wq*256+256)
// = 16 chunks of 16 v. k-map (same bijection both operands): v=16c+8g+j.
// LDS 80 KB: per-wave A ring-3 (2 KB slots) + X ring-2 -> 2 blocks/CU.
// Phase A per chunk: 2 gll16 (A rows, 128B segs) + 2 gll16 (X, 1KB contig),
// counted vmcnt, ds_read + cvt -> bfr[c] retained, 1 MFMA. Fully unrolled
// (bfr must be static-indexed).  Phase B: 2 gll16 (x1) per chunk, vmcnt(2),
// MFMA vs bfr[c].  Cross-wave K reduce via Lred overlay on SA.
// ---------------------------------------------------------------------------
__global__ __launch_bounds__(512, 4) void gcn_chain_kernel(
    const float* __restrict__ A0g, const float* __restrict__ A1g,
    const float* __restrict__ A2g, const float* __restrict__ Xg,
    float* __restrict__ x1a, float* __restrict__ x2a,
    float* __restrict__ x1b, float* __restrict__ x2b,
    float* __restrict__ x1c, float* __restrict__ x2c,
    unsigned* __restrict__ cnt) {
  __shared__ float SA[8][3][16][32];  // 48 KB (A staging; Lred overlay)
  __shared__ float SX[8][2][16][32];  // 32 KB (X / x1 staging)

  const int bid  = blockIdx.x;   // 512 blocks = 2/CU co-resident
  const int n    = bid >> 6;
  const int wcol = (bid & 63) * 32;
  const int t    = threadIdx.x;
  const int wq   = t >> 6;       // wave id = K eighth
  const int lane = t & 63;
  const int g    = lane >> 5;
  const int mn   = lane & 31;    // m (=l) for A-op, n (=w) for B-op

  const float* __restrict__ Xsrc =
      Xg + (size_t)n * V * CIN + wq * 256 * CIN + lane * 4;

  f32x16 acc;

  auto reduce_store = [&](float* __restrict__ Out) {
    __syncthreads();
    float(*Lred)[32][33] = reinterpret_cast<float(*)[32][33]>(&SA[0][0][0][0]);
#pragma unroll
    for (int r = 0; r < 16; ++r)
      Lred[wq][(r & 3) + 8 * (r >> 2) + 4 * g][mn] = acc[r];
    __syncthreads();
    const int w  = t >> 4;
    const int l0 = (t & 15) * 2;
    float2 o;
    o.x = 0.f;
    o.y = 0.f;
#pragma unroll
    for (int k = 0; k < 8; ++k) {
      o.x += Lred[k][l0][w];
      o.y += Lred[k][l0 + 1][w];
    }
    *(float2*)(Out + ((size_t)n * V + wcol + w) * CIN + l0) = o;
    __syncthreads();  // protect overlay before SA is restaged
  };

  auto grid_sync = [&](unsigned target) {
    __threadfence();  // drain stores to device coherence point
    __syncthreads();
    if (t == 0) {
      __hip_atomic_fetch_add(cnt, 1u, __ATOMIC_RELEASE,
                             __HIP_MEMORY_SCOPE_AGENT);
      while (__hip_atomic_load(cnt, __ATOMIC_ACQUIRE,
                               __HIP_MEMORY_SCOPE_AGENT) < target)
        __builtin_amdgcn_s_sleep(32);
    }
    __syncthreads();
    __threadfence();
  };

#define WV(N)                                             \
  do {                                                    \
    asm volatile("s_waitcnt vmcnt(" #N ")" ::: "memory"); \
    __builtin_amdgcn_sched_barrier(0);                    \
  } while (0)

#define STGA(SL, C)                                          \
  do {                                                       \
    const float* a_ = Apl + (size_t)(C) * (16 * V);          \
    gll16(a_, &SA[wq][SL][0][0]);                            \
    gll16(a_ + (size_t)8 * V, &SA[wq][SL][8][0]);            \
  } while (0)

#define STGX(SL, C)                                          \
  do {                                                       \
    const float* x_ = Xsrc + (C) * (16 * CIN);               \
    gll16(x_, &SX[wq][SL][0][0]);                            \
    gll16(x_ + 256, &SX[wq][SL][8][0]);                      \
  } while (0)

#define STGY(SL, C)                                          \
  do {                                                       \
    const float* y_ = Yp + (C) * (16 * CIN);                 \
    gll16(y_, &SX[wq][SL][0][0]);                            \
    gll16(y_ + 256, &SX[wq][SL][8][0]);                      \
  } while (0)

#define CMPA(ASL, XSL, C)                                                 \
  do {                                                                    \
    float a8[8], x8[8];                                                   \
    _Pragma("unroll") for (int j = 0; j < 8; ++j) {                       \
      a8[j] = SA[wq][ASL][8 * g + j][mn];                                 \
      x8[j] = SX[wq][XSL][8 * g + j][mn];                                 \
    }                                                                     \
    bf16x8 aop_;                                                          \
    _Pragma("unroll") for (int j = 0; j < 8; ++j) {                       \
      aop_[j]   = f2bf(x8[j]);                                            \
      bfr[C][j] = f2bf(a8[j]);                                            \
    }                                                                     \
    acc = __builtin_amdgcn_mfma_f32_32x32x16_bf16(aop_, bfr[C], acc,      \
                                                  0, 0, 0);               \
  } while (0)

#define CMPB(XSL, C)                                                      \
  do {                                                                    \
    float y8[8];                                                          \
    _Pragma("unroll") for (int j = 0; j < 8; ++j)                         \
      y8[j] = SX[wq][XSL][8 * g + j][mn];                                 \
    bf16x8 aop_;                                                          \
    _Pragma("unroll") for (int j = 0; j < 8; ++j) aop_[j] = f2bf(y8[j]);  \
    acc = __builtin_amdgcn_mfma_f32_32x32x16_bf16(aop_, bfr[C], acc,      \
                                                  0, 0, 0);               \
  } while (0)

#pragma unroll 1
  for (int ch = 0; ch < 3; ++ch) {
    const float* __restrict__ Adj = ch == 0 ? A0g : (ch == 1 ? A1g : A2g);
    float* __restrict__ X1 = ch == 0 ? x1a : (ch == 1 ? x1b : x1c);
    float* __restrict__ X2 = ch == 0 ? x2a : (ch == 1 ? x2b : x2c);
    const float* __restrict__ Apl =
        Adj + (size_t)n * V * V + (size_t)(wq * 256) * V + wcol +
        (size_t)(lane >> 3) * V + (lane & 7) * 4;

    bf16x8 bfr[16];  // retained A fragments: 64 VGPR/lane

    // -------- Phase A: hop1, A read ONCE, fragments retained --------
#pragma unroll
    for (int r = 0; r < 16; ++r) acc[r] = 0.f;
    STGA(0, 0); STGX(0, 0); STGA(1, 1);
    STGX(1, 1);  STGA(2, 2);  WV(6); CMPA(0, 0, 0);
    STGX(0, 2);  STGA(0, 3);  WV(6); CMPA(1, 1, 1);
    STGX(1, 3);  STGA(1, 4);  WV(6); CMPA(2, 0, 2);
    STGX(0, 4);  STGA(2, 5);  WV(6); CMPA(0, 1, 3);
    STGX(1, 5);  STGA(0, 6);  WV(6); CMPA(1, 0, 4);
    STGX(0, 6);  STGA(1, 7);  WV(6); CMPA(2, 1, 5);
    STGX(1, 7);  STGA(2, 8);  WV(6); CMPA(0, 0, 6);
    STGX(0, 8);  STGA(0, 9);  WV(6); CMPA(1, 1, 7);
    STGX(1, 9);  STGA(1, 10); WV(6); CMPA(2, 0, 8);
    STGX(0, 10); STGA(2, 11); WV(6); CMPA(0, 1, 9);
    STGX(1, 11); STGA(0, 12); WV(6); CMPA(1, 0, 10);
    STGX(0, 12); STGA(1, 13); WV(6); CMPA(2, 1, 11);
    STGX(1, 13); STGA(2, 14); WV(6); CMPA(0, 0, 12);
    STGX(0, 14); STGA(0, 15); WV(6); CMPA(1, 1, 13);
    STGX(1, 15);              WV(4); CMPA(2, 0, 14);
                              WV(0); CMPA(0, 1, 15);
    reduce_store(X1);
    grid_sync(512u * (unsigned)(ch + 1));

    // -------- Phase B: hop2 from retained fragments, zero A traffic -----
    const float* __restrict__ Yp =
        X1 + (size_t)n * V * CIN + wq * 256 * CIN + lane * 4;
#pragma unroll
    for (int r = 0; r < 16; ++r) acc[r] = 0.f;
    STGY(0, 0);
    STGY(1, 1);  WV(2); CMPB(0, 0);
    STGY(0, 2);  WV(2); CMPB(1, 1);
    STGY(1, 3);  WV(2); CMPB(0, 2);
    STGY(0, 4);  WV(2); CMPB(1, 3);
    STGY(1, 5);  WV(2); CMPB(0, 4);
    STGY(0, 6);  WV(2); CMPB(1, 5);
    STGY(1, 7);  WV(2); CMPB(0, 6);
    STGY(0, 8);  WV(2); CMPB(1, 7);
    STGY(1, 9);  WV(2); CMPB(0, 8);
    STGY(0, 10); WV(2); CMPB(1, 9);
    STGY(1, 11); WV(2); CMPB(0, 10);
    STGY(0, 12); WV(2); CMPB(1, 11);
    STGY(1, 13); WV(2); CMPB(0, 12);
    STGY(0, 14); WV(2); CMPB(1, 13);
    STGY(1, 15); WV(2); CMPB(0, 14);
                 WV(0); CMPB(1, 15);
    reduce_store(X2);
    // no inter-chain sync needed: next phase A reads only A(ch+1) and x
  }

#undef WV
#undef STGA
#undef STGX
#undef STGY
#undef CMPA
#undef CMPB
}

// ---------------------------------------------------------------------------
// conv 1x1 + bias + BN batch-stats partials (unchanged, passing).
// ---------------------------------------------------------------------------
__global__ __launch_bounds__(256) void conv_bn_stats_kernel(
    const float* __restrict__ W, const float* __restrict__ bias,
    const float* __restrict__ p0, const float* __restrict__ p1,
    const float* __restrict__ p2, const float* __restrict__ p3,
    const float* __restrict__ p4, const float* __restrict__ p5,
    const float* __restrict__ p6, float* __restrict__ hout,
    float* __restrict__ stats) {
  __shared__ float Wl[COUT * CTOT];
  __shared__ float Fl[64 * CTOT];
  const int t = threadIdx.x;
  const int R0 = blockIdx.x * 64;

#pragma unroll
  for (int s = 0; s < 14; ++s) {
    int fl = t + s * 256;
    int o = fl / 56, c4 = fl % 56;
    float4 wv = *(const float4*)(W + o * CTOT + c4 * 4);
    int c = c4 * 4;
    int csw = c ^ (((o >> 2) & 7) << 2);
    *(float4*)&Wl[o * CTOT + csw] = wv;
  }
  const float* parts[7] = {p0, p1, p2, p3, p4, p5, p6};
#pragma unroll
  for (int p = 0; p < 7; ++p) {
    const float* __restrict__ src = parts[p] + (size_t)R0 * CIN;
#pragma unroll
    for (int s = 0; s < 2; ++s) {
      int fl = t + s * 256;
      int r = fl >> 3, c4 = fl & 7;
      float4 v = *(const float4*)(src + r * CIN + c4 * 4);
      int c = p * 32 + c4 * 4;
      int csw = c ^ (((r >> 2) & 7) << 2);
      *(float4*)&Fl[r * CTOT + csw] = v;
    }
  }
  __syncthreads();

  const int rg = t & 15, og = t >> 4;
  const int r0 = rg * 4, o0 = og * 4;
  float acc[4][4];
#pragma unroll
  for (int i = 0; i < 4; ++i)
#pragma unroll
    for (int j = 0; j < 4; ++j) acc[i][j] = bias[o0 + j];

  const int fsw = (rg & 7) << 2;
  const int wsw = (og & 7) << 2;
  for (int cc = 0; cc < CTOT; cc += 4) {
    float4 f[4], w[4];
#pragma unroll
    for (int i = 0; i < 4; ++i)
      f[i] = *(const float4*)&Fl[(r0 + i) * CTOT + (cc ^ fsw)];
#pragma unroll
    for (int j = 0; j < 4; ++j)
      w[j] = *(const float4*)&Wl[(o0 + j) * CTOT + (cc ^ wsw)];
#pragma unroll
    for (int i = 0; i < 4; ++i)
#pragma unroll
      for (int j = 0; j < 4; ++j)
        acc[i][j] += f[i].x * w[j].x + f[i].y * w[j].y + f[i].z * w[j].z +
                     f[i].w * w[j].w;
  }

#pragma unroll
  for (int i = 0; i < 4; ++i) {
    *(float4*)(hout + (size_t)(R0 + r0 + i) * COUT + o0) =
        make_float4(acc[i][0], acc[i][1], acc[i][2], acc[i][3]);
  }

  __syncthreads();
  float* red = Fl;
#pragma unroll
  for (int j = 0; j < 4; ++j) {
    float s = acc[0][j] + acc[1][j] + acc[2][j] + acc[3][j];
    float qq = acc[0][j] * acc[0][j] + acc[1][j] * acc[1][j] +
               acc[2][j] * acc[2][j] + acc[3][j] * acc[3][j];
    red[(o0 + j) * 16 + rg] = s;
    red[1024 + (o0 + j) * 16 + rg] = qq;
  }
  __syncthreads();
  if (t < 128) {
    int o = t & 63, which = t >> 6;
    const float* b = red + which * 1024 + o * 16;
    float v = 0.f;
#pragma unroll
    for (int k = 0; k < 16; ++k) v += b[k];
    atomicAdd(stats + which * COUT + o, v);
  }
}

// ---------------------------------------------------------------------------
__global__ __launch_bounds__(256) void bn_apply_kernel(
    float* __restrict__ hout, const float* __restrict__ stats,
    const float* __restrict__ gamma, const float* __restrict__ beta) {
  const int i4 = blockIdx.x * 256 + threadIdx.x;
  const int oi = i4 & 15;
  float4 h = ((const float4*)hout)[i4];
  const float4 s = ((const float4*)stats)[oi];
  const float4 q = ((const float4*)(stats + COUT))[oi];
  const float4 g = ((const float4*)gamma)[oi];
  const float4 bb = ((const float4*)beta)[oi];
  const float inv = 1.f / 16384.f;
  float m, vv, rs;
  m = s.x * inv; vv = q.x * inv - m * m; rs = rsqrtf(vv + 1e-5f);
  h.x = (h.x - m) * rs * g.x + bb.x;
  m = s.y * inv; vv = q.y * inv - m * m; rs = rsqrtf(vv + 1e-5f);
  h.y = (h.y - m) * rs * g.y + bb.y;
  m = s.z * inv; vv = q.z * inv - m * m; rs = rsqrtf(vv + 1e-5f);
  h.z = (h.z - m) * rs * g.z + bb.z;
  m = s.w * inv; vv = q.w * inv - m * m; rs = rsqrtf(vv + 1e-5f);
  h.w = (h.w - m) * rs * g.w + bb.w;
  ((float4*)hout)[i4] = h;
}

// ---------------------------------------------------------------------------
extern "C" void kernel_launch(void* const* d_in, const int* in_sizes, int n_in,
                              void* d_out, int out_size, void* d_ws,
                              size_t ws_size, hipStream_t stream) {
  const float* x     = (const float*)d_in[0];
  const float* A0    = (const float*)d_in[1];
  const float* A1    = (const float*)d_in[2];
  const float* A2    = (const float*)d_in[3];
  const float* W     = (const float*)d_in[4];
  const float* b     = (const float*)d_in[5];
  const float* gamma = (const float*)d_in[6];
  const float* beta  = (const float*)d_in[7];
  float* out = (float*)d_out;

  char* ws = (char*)d_ws;
  float* stats = (float*)ws;                 // 2*64 floats
  unsigned* cnt = (unsigned*)(ws + 2048);    // grid-barrier counter
  const size_t BUF = (size_t)NB * V * CIN;   // 524288 floats (2 MB)
  float* x1_0 = (float*)(ws + 4096);
  float* x2_0 = x1_0 + BUF;
  float* x1_1 = x2_0 + BUF;
  float* x2_1 = x1_1 + BUF;
  float* x1_2 = x2_1 + BUF;
  float* x2_2 = x1_2 + BUF;

  hipMemsetAsync(ws, 0, 4096, stream);  // stats + barrier counter

  gcn_chain_kernel<<<dim3(512), dim3(512), 0, stream>>>(
      A0, A1, A2, x, x1_0, x2_0, x1_1, x2_1, x1_2, x2_2, cnt);

  conv_bn_stats_kernel<<<dim3(256), dim3(256), 0, stream>>>(
      W, b, x, x1_0, x2_0, x1_1, x2_1, x1_2, x2_2, out, stats);
  bn_apply_kernel<<<dim3(1024), dim3(256), 0, stream>>>(out, stats, gamma,
                                                        beta);
}

// Round 10
// 226.877 us; speedup vs baseline: 3.6968x; 3.6968x over previous
//
#include <hip/hip_runtime.h>
#include <hip/hip_bf16.h>

// GraphConvNet: x:[8,2048,32] f32, A0/A1/A2:[8,2048,2048] f32 row-normalized,
// W:[64,224], b/gamma/beta:[64].
// nconv: out[n,w,l] = sum_v A[n,v,w] * x[n,v,l]
// feat = concat([x, x1_0, x2_0, x1_1, x2_1, x1_2, x2_2])  (224 ch)
// h = feat @ W^T + b ; BN over (n,v) per channel; out f32 [8,2048,64]
//
// Schedule: S1 = h1(A0)||h1(A1)||h1(A2)  (1536 blocks, one kernel)
//           S2 = h2(A0)||h2(A1)||h2(A2)  (1536 blocks, one kernel)
// Register-ring nconv (17 KB LDS, ~68 VGPR) -> 6 blocks/CU, 24 waves/CU:
// 3x the TLP of prior rounds, 1/3 the launch/ramp overhead.

#define V    2048
#define NB   8
#define CIN  32
#define COUT 64
#define CTOT 224

typedef __attribute__((ext_vector_type(8))) short bf16x8;
typedef __attribute__((ext_vector_type(16))) float f32x16;

static __device__ __forceinline__ short f2bf(float f) {
  __hip_bfloat16 h = __float2bfloat16(f);  // RNE
  return *reinterpret_cast<short*>(&h);
}

// ---------------------------------------------------------------------------
// Triple-job nconv via MFMA 32x32x16 bf16, register-ring pipelined.
// grid = 1536: job j = bid>>9 (which A), sub = bid&511 -> (n, 32-w strip).
// Per job-block: 4 waves, each owns a K-quarter (512 v) of one (n, strip).
// Register ring depth 4 (named slots, static indexing). Per k-step: 16
// global_load_dword (each = 2 x 128B lines, coalesced), s_waitcnt vmcnt(48)
// => 3 chunks in flight, cvt to bf16, one MFMA.
// k-slot map (same bijection both operands => correct): v = v0 + 8g + j.
// ---------------------------------------------------------------------------
__global__ __launch_bounds__(256) void nconv3_kernel(
    const float* __restrict__ A0g, const float* __restrict__ A1g,
    const float* __restrict__ A2g, const float* __restrict__ I0,
    const float* __restrict__ I1, const float* __restrict__ I2,
    float* __restrict__ O0, float* __restrict__ O1, float* __restrict__ O2) {
  __shared__ float Lred[4][32][33];  // cross-wave reduce only (~17 KB)

  const int bid  = blockIdx.x;    // 1536 blocks
  const int job  = bid >> 9;      // which adjacency/chain
  const int sub  = bid & 511;
  const int n    = sub >> 6;
  const int ws   = (sub & 63) * 32;
  const int t    = threadIdx.x;
  const int q    = t >> 6;        // wave id = K quarter
  const int lane = t & 63;
  const int g    = lane >> 5;
  const int mn   = lane & 31;     // m (=l) for A-op, n (=w) for B-op

  const float* Adj  = job == 0 ? A0g : (job == 1 ? A1g : A2g);
  const float* Xin  = job == 0 ? I0 : (job == 1 ? I1 : I2);
  float*       Xout = job == 0 ? O0 : (job == 1 ? O1 : O2);

  // per-lane bases; chunk c adds c*16 rows
  const float* __restrict__ Ap =
      Adj + (size_t)n * V * V + (size_t)(q * 512 + 8 * g) * V + ws + mn;
  const float* __restrict__ Xp =
      Xin + (size_t)n * V * CIN + (q * 512 + 8 * g) * CIN + mn;

  float a0[8], a1[8], a2[8], a3[8];
  float x0[8], x1[8], x2[8], x3[8];

#define STAGE(S, C)                                                  \
  do {                                                               \
    const float* __restrict__ ap_ = Ap + (size_t)(C) * (16 * V);     \
    const float* __restrict__ xp_ = Xp + (C) * (16 * CIN);           \
    _Pragma("unroll") for (int j = 0; j < 8; ++j) {                  \
      a##S[j] = ap_[(size_t)j * V];                                  \
      x##S[j] = xp_[j * CIN];                                        \
    }                                                                \
  } while (0)

#define WAITV(N)                                         \
  do {                                                   \
    asm volatile("s_waitcnt vmcnt(" #N ")" ::: "memory");\
    __builtin_amdgcn_sched_barrier(0);                   \
  } while (0)

  f32x16 acc;
#pragma unroll
  for (int r = 0; r < 16; ++r) acc[r] = 0.f;

#define COMPUTE(S)                                                   \
  do {                                                               \
    bf16x8 aop_, bop_;                                               \
    _Pragma("unroll") for (int j = 0; j < 8; ++j) {                  \
      aop_[j] = f2bf(x##S[j]); /* X^T is the A operand */            \
      bop_[j] = f2bf(a##S[j]); /* Adj   is the B operand */          \
    }                                                                \
    acc = __builtin_amdgcn_mfma_f32_32x32x16_bf16(aop_, bop_, acc,   \
                                                  0, 0, 0);          \
  } while (0)

  STAGE(0, 0);
  STAGE(1, 1);
  STAGE(2, 2);
#pragma unroll 1
  for (int it = 0; it < 7; ++it) {  // computes chunks 0..27, stages 3..30
    const int kb = it * 4;
    STAGE(3, kb + 3); WAITV(48); COMPUTE(0);
    STAGE(0, kb + 4); WAITV(48); COMPUTE(1);
    STAGE(1, kb + 5); WAITV(48); COMPUTE(2);
    STAGE(2, kb + 6); WAITV(48); COMPUTE(3);
  }
  STAGE(3, 31); WAITV(48); COMPUTE(0);  // chunk 28
  WAITV(32); COMPUTE(1);                // chunk 29
  WAITV(16); COMPUTE(2);                // chunk 30
  WAITV(0);  COMPUTE(3);                // chunk 31

#undef STAGE
#undef WAITV
#undef COMPUTE

  // ---- cross-wave K reduce ----
#pragma unroll
  for (int r = 0; r < 16; ++r) {
    // C^T[l][w]: row l = (r&3)+8*(r>>2)+4*g, col w = mn
    Lred[q][(r & 3) + 8 * (r >> 2) + 4 * g][mn] = acc[r];
  }
  __syncthreads();
  const int w  = t >> 3;
  const int l4 = t & 7;
  float4 o;
  float* op = &o.x;
#pragma unroll
  for (int i = 0; i < 4; ++i) {
    op[i] = Lred[0][l4 * 4 + i][w] + Lred[1][l4 * 4 + i][w] +
            Lred[2][l4 * 4 + i][w] + Lred[3][l4 * 4 + i][w];
  }
  *(float4*)(Xout + ((size_t)n * V + ws + w) * CIN + l4 * 4) = o;
}

// ---------------------------------------------------------------------------
// conv 1x1 + bias + BN batch-stats partials (unchanged, passing).
// ---------------------------------------------------------------------------
__global__ __launch_bounds__(256) void conv_bn_stats_kernel(
    const float* __restrict__ W, const float* __restrict__ bias,
    const float* __restrict__ p0, const float* __restrict__ p1,
    const float* __restrict__ p2, const float* __restrict__ p3,
    const float* __restrict__ p4, const float* __restrict__ p5,
    const float* __restrict__ p6, float* __restrict__ hout,
    float* __restrict__ stats) {
  __shared__ float Wl[COUT * CTOT];
  __shared__ float Fl[64 * CTOT];
  const int t = threadIdx.x;
  const int R0 = blockIdx.x * 64;

#pragma unroll
  for (int s = 0; s < 14; ++s) {
    int fl = t + s * 256;
    int o = fl / 56, c4 = fl % 56;
    float4 wv = *(const float4*)(W + o * CTOT + c4 * 4);
    int c = c4 * 4;
    int csw = c ^ (((o >> 2) & 7) << 2);
    *(float4*)&Wl[o * CTOT + csw] = wv;
  }
  const float* parts[7] = {p0, p1, p2, p3, p4, p5, p6};
#pragma unroll
  for (int p = 0; p < 7; ++p) {
    const float* __restrict__ src = parts[p] + (size_t)R0 * CIN;
#pragma unroll
    for (int s = 0; s < 2; ++s) {
      int fl = t + s * 256;
      int r = fl >> 3, c4 = fl & 7;
      float4 v = *(const float4*)(src + r * CIN + c4 * 4);
      int c = p * 32 + c4 * 4;
      int csw = c ^ (((r >> 2) & 7) << 2);
      *(float4*)&Fl[r * CTOT + csw] = v;
    }
  }
  __syncthreads();

  const int rg = t & 15, og = t >> 4;
  const int r0 = rg * 4, o0 = og * 4;
  float acc[4][4];
#pragma unroll
  for (int i = 0; i < 4; ++i)
#pragma unroll
    for (int j = 0; j < 4; ++j) acc[i][j] = bias[o0 + j];

  const int fsw = (rg & 7) << 2;
  const int wsw = (og & 7) << 2;
  for (int cc = 0; cc < CTOT; cc += 4) {
    float4 f[4], w[4];
#pragma unroll
    for (int i = 0; i < 4; ++i)
      f[i] = *(const float4*)&Fl[(r0 + i) * CTOT + (cc ^ fsw)];
#pragma unroll
    for (int j = 0; j < 4; ++j)
      w[j] = *(const float4*)&Wl[(o0 + j) * CTOT + (cc ^ wsw)];
#pragma unroll
    for (int i = 0; i < 4; ++i)
#pragma unroll
      for (int j = 0; j < 4; ++j)
        acc[i][j] += f[i].x * w[j].x + f[i].y * w[j].y + f[i].z * w[j].z +
                     f[i].w * w[j].w;
  }

#pragma unroll
  for (int i = 0; i < 4; ++i) {
    *(float4*)(hout + (size_t)(R0 + r0 + i) * COUT + o0) =
        make_float4(acc[i][0], acc[i][1], acc[i][2], acc[i][3]);
  }

  __syncthreads();
  float* red = Fl;
#pragma unroll
  for (int j = 0; j < 4; ++j) {
    float s = acc[0][j] + acc[1][j] + acc[2][j] + acc[3][j];
    float qq = acc[0][j] * acc[0][j] + acc[1][j] * acc[1][j] +
               acc[2][j] * acc[2][j] + acc[3][j] * acc[3][j];
    red[(o0 + j) * 16 + rg] = s;
    red[1024 + (o0 + j) * 16 + rg] = qq;
  }
  __syncthreads();
  if (t < 128) {
    int o = t & 63, which = t >> 6;
    const float* b = red + which * 1024 + o * 16;
    float v = 0.f;
#pragma unroll
    for (int k = 0; k < 16; ++k) v += b[k];
    atomicAdd(stats + which * COUT + o, v);
  }
}

// ---------------------------------------------------------------------------
__global__ __launch_bounds__(256) void bn_apply_kernel(
    float* __restrict__ hout, const float* __restrict__ stats,
    const float* __restrict__ gamma, const float* __restrict__ beta) {
  const int i4 = blockIdx.x * 256 + threadIdx.x;
  const int oi = i4 & 15;
  float4 h = ((const float4*)hout)[i4];
  const float4 s = ((const float4*)stats)[oi];
  const float4 q = ((const float4*)(stats + COUT))[oi];
  const float4 g = ((const float4*)gamma)[oi];
  const float4 bb = ((const float4*)beta)[oi];
  const float inv = 1.f / 16384.f;
  float m, vv, rs;
  m = s.x * inv; vv = q.x * inv - m * m; rs = rsqrtf(vv + 1e-5f);
  h.x = (h.x - m) * rs * g.x + bb.x;
  m = s.y * inv; vv = q.y * inv - m * m; rs = rsqrtf(vv + 1e-5f);
  h.y = (h.y - m) * rs * g.y + bb.y;
  m = s.z * inv; vv = q.z * inv - m * m; rs = rsqrtf(vv + 1e-5f);
  h.z = (h.z - m) * rs * g.z + bb.z;
  m = s.w * inv; vv = q.w * inv - m * m; rs = rsqrtf(vv + 1e-5f);
  h.w = (h.w - m) * rs * g.w + bb.w;
  ((float4*)hout)[i4] = h;
}

// ---------------------------------------------------------------------------
extern "C" void kernel_launch(void* const* d_in, const int* in_sizes, int n_in,
                              void* d_out, int out_size, void* d_ws,
                              size_t ws_size, hipStream_t stream) {
  const float* x     = (const float*)d_in[0];
  const float* A0    = (const float*)d_in[1];
  const float* A1    = (const float*)d_in[2];
  const float* A2    = (const float*)d_in[3];
  const float* W     = (const float*)d_in[4];
  const float* b     = (const float*)d_in[5];
  const float* gamma = (const float*)d_in[6];
  const float* beta  = (const float*)d_in[7];
  float* out = (float*)d_out;

  char* ws = (char*)d_ws;
  float* stats = (float*)ws;
  const size_t BUF = (size_t)NB * V * CIN;  // 524288 floats (2 MB)
  float* x1_0 = (float*)(ws + 4096);
  float* x2_0 = x1_0 + BUF;
  float* x1_1 = x2_0 + BUF;
  float* x2_1 = x1_1 + BUF;
  float* x1_2 = x2_1 + BUF;
  float* x2_2 = x1_2 + BUF;

  hipMemsetAsync(stats, 0, 2 * COUT * sizeof(float), stream);

  dim3 blk(256);
  // S1: all three hop1s (independent, all read x) in one 1536-block kernel.
  nconv3_kernel<<<dim3(1536), blk, 0, stream>>>(
      A0, A1, A2, x, x, x, x1_0, x1_1, x1_2);
  // S2: all three hop2s (independent) in one 1536-block kernel.
  nconv3_kernel<<<dim3(1536), blk, 0, stream>>>(
      A0, A1, A2, x1_0, x1_1, x1_2, x2_0, x2_1, x2_2);

  conv_bn_stats_kernel<<<dim3(256), blk, 0, stream>>>(
      W, b, x, x1_0, x2_0, x1_1, x2_1, x1_2, x2_2, out, stats);
  bn_apply_kernel<<<dim3(1024), blk, 0, stream>>>(out, stats, gamma, beta);
}

// Round 11
// 215.147 us; speedup vs baseline: 3.8984x; 1.0545x over previous
//
#include <hip/hip_runtime.h>
#include <hip/hip_bf16.h>

// GraphConvNet: x:[8,2048,32] f32, A0/A1/A2:[8,2048,2048] f32 row-normalized,
// W:[64,224], b/gamma/beta:[64].
// nconv: out[n,w,l] = sum_v A[n,v,w] * x[n,v,l]
// feat = concat([x, x1_0, x2_0, x1_1, x2_1, x1_2, x2_2])  (224 ch)
// h = feat @ W^T + b ; BN over (n,v) per channel; out f32 [8,2048,64]
//
// Round 11: r4 register-ring nconv + NON-TEMPORAL A loads (nt bypasses
// L2/L3 allocation; A is a zero-reuse 134 MB stream per pass; allocation
// thrash is the suspected 4.3-vs-6.3 TB/s gap). X stays cached (64x reuse).

#define V    2048
#define NB   8
#define CIN  32
#define COUT 64
#define CTOT 224

typedef __attribute__((ext_vector_type(8))) short bf16x8;
typedef __attribute__((ext_vector_type(16))) float f32x16;

static __device__ __forceinline__ short f2bf(float f) {
  __hip_bfloat16 h = __float2bfloat16(f);  // RNE
  return *reinterpret_cast<short*>(&h);
}

// ---------------------------------------------------------------------------
// nconv via MFMA 32x32x16 bf16, register-ring pipelined, no LDS in main loop.
// Block: 4 waves, each owns a K-quarter (512 v) of one (n, 32-w strip).
// Register ring depth 4 (named slots, static indexing only).
// Per k-step: 8 nt A-loads + 8 cached X-loads (each = 2 x 128B, coalesced),
// s_waitcnt vmcnt(48) => 3 chunks in flight, cvt to bf16, one MFMA.
// k-slot map (same bijection both operands => correct): v = v0 + 8g + j.
// ---------------------------------------------------------------------------
__global__ __launch_bounds__(256) void nconv_mfma_kernel(
    const float* __restrict__ Adj, const float* __restrict__ Xin,
    float* __restrict__ Xout) {
  __shared__ float Lred[4][32][33];  // cross-wave reduce only (~17 KB)

  const int bid  = blockIdx.x;    // 512 blocks
  const int n    = bid >> 6;
  const int ws   = (bid & 63) * 32;
  const int t    = threadIdx.x;
  const int q    = t >> 6;        // wave id = K quarter
  const int lane = t & 63;
  const int g    = lane >> 5;
  const int mn   = lane & 31;     // m (=l) for A-op, n (=w) for B-op

  // per-lane bases; chunk c adds c*16 rows
  const float* __restrict__ Ap =
      Adj + (size_t)n * V * V + (size_t)(q * 512 + 8 * g) * V + ws + mn;
  const float* __restrict__ Xp =
      Xin + (size_t)n * V * CIN + (q * 512 + 8 * g) * CIN + mn;

  float a0[8], a1[8], a2[8], a3[8];
  float x0[8], x1[8], x2[8], x3[8];

#define STAGE(S, C)                                                  \
  do {                                                               \
    const float* __restrict__ ap_ = Ap + (size_t)(C) * (16 * V);     \
    const float* __restrict__ xp_ = Xp + (C) * (16 * CIN);           \
    _Pragma("unroll") for (int j = 0; j < 8; ++j) {                  \
      a##S[j] = __builtin_nontemporal_load(ap_ + (size_t)j * V);     \
      x##S[j] = xp_[j * CIN];                                        \
    }                                                                \
  } while (0)

#define WAITV(N)                                         \
  do {                                                   \
    asm volatile("s_waitcnt vmcnt(" #N ")" ::: "memory");\
    __builtin_amdgcn_sched_barrier(0);                   \
  } while (0)

  f32x16 acc;
#pragma unroll
  for (int r = 0; r < 16; ++r) acc[r] = 0.f;

#define COMPUTE(S)                                                   \
  do {                                                               \
    bf16x8 aop_, bop_;                                               \
    _Pragma("unroll") for (int j = 0; j < 8; ++j) {                  \
      aop_[j] = f2bf(x##S[j]); /* X^T is the A operand */            \
      bop_[j] = f2bf(a##S[j]); /* Adj   is the B operand */          \
    }                                                                \
    acc = __builtin_amdgcn_mfma_f32_32x32x16_bf16(aop_, bop_, acc,   \
                                                  0, 0, 0);          \
  } while (0)

  STAGE(0, 0);
  STAGE(1, 1);
  STAGE(2, 2);
#pragma unroll 1
  for (int it = 0; it < 7; ++it) {  // computes chunks 0..27, stages 3..30
    const int kb = it * 4;
    STAGE(3, kb + 3); WAITV(48); COMPUTE(0);
    STAGE(0, kb + 4); WAITV(48); COMPUTE(1);
    STAGE(1, kb + 5); WAITV(48); COMPUTE(2);
    STAGE(2, kb + 6); WAITV(48); COMPUTE(3);
  }
  STAGE(3, 31); WAITV(48); COMPUTE(0);  // chunk 28
  WAITV(32); COMPUTE(1);                // chunk 29
  WAITV(16); COMPUTE(2);                // chunk 30
  WAITV(0);  COMPUTE(3);                // chunk 31

#undef STAGE
#undef WAITV
#undef COMPUTE

  // ---- cross-wave K reduce ----
#pragma unroll
  for (int r = 0; r < 16; ++r) {
    // C^T[l][w]: row l = (r&3)+8*(r>>2)+4*g, col w = mn
    Lred[q][(r & 3) + 8 * (r >> 2) + 4 * g][mn] = acc[r];
  }
  __syncthreads();
  const int w  = t >> 3;
  const int l4 = t & 7;
  float4 o;
  float* op = &o.x;
#pragma unroll
  for (int i = 0; i < 4; ++i) {
    op[i] = Lred[0][l4 * 4 + i][w] + Lred[1][l4 * 4 + i][w] +
            Lred[2][l4 * 4 + i][w] + Lred[3][l4 * 4 + i][w];
  }
  *(float4*)(Xout + ((size_t)n * V + ws + w) * CIN + l4 * 4) = o;
}

// ---------------------------------------------------------------------------
// conv 1x1 + bias + BN batch-stats partials (unchanged, passing).
// ---------------------------------------------------------------------------
__global__ __launch_bounds__(256) void conv_bn_stats_kernel(
    const float* __restrict__ W, const float* __restrict__ bias,
    const float* __restrict__ p0, const float* __restrict__ p1,
    const float* __restrict__ p2, const float* __restrict__ p3,
    const float* __restrict__ p4, const float* __restrict__ p5,
    const float* __restrict__ p6, float* __restrict__ hout,
    float* __restrict__ stats) {
  __shared__ float Wl[COUT * CTOT];
  __shared__ float Fl[64 * CTOT];
  const int t = threadIdx.x;
  const int R0 = blockIdx.x * 64;

#pragma unroll
  for (int s = 0; s < 14; ++s) {
    int fl = t + s * 256;
    int o = fl / 56, c4 = fl % 56;
    float4 wv = *(const float4*)(W + o * CTOT + c4 * 4);
    int c = c4 * 4;
    int csw = c ^ (((o >> 2) & 7) << 2);
    *(float4*)&Wl[o * CTOT + csw] = wv;
  }
  const float* parts[7] = {p0, p1, p2, p3, p4, p5, p6};
#pragma unroll
  for (int p = 0; p < 7; ++p) {
    const float* __restrict__ src = parts[p] + (size_t)R0 * CIN;
#pragma unroll
    for (int s = 0; s < 2; ++s) {
      int fl = t + s * 256;
      int r = fl >> 3, c4 = fl & 7;
      float4 v = *(const float4*)(src + r * CIN + c4 * 4);
      int c = p * 32 + c4 * 4;
      int csw = c ^ (((r >> 2) & 7) << 2);
      *(float4*)&Fl[r * CTOT + csw] = v;
    }
  }
  __syncthreads();

  const int rg = t & 15, og = t >> 4;
  const int r0 = rg * 4, o0 = og * 4;
  float acc[4][4];
#pragma unroll
  for (int i = 0; i < 4; ++i)
#pragma unroll
    for (int j = 0; j < 4; ++j) acc[i][j] = bias[o0 + j];

  const int fsw = (rg & 7) << 2;
  const int wsw = (og & 7) << 2;
  for (int cc = 0; cc < CTOT; cc += 4) {
    float4 f[4], w[4];
#pragma unroll
    for (int i = 0; i < 4; ++i)
      f[i] = *(const float4*)&Fl[(r0 + i) * CTOT + (cc ^ fsw)];
#pragma unroll
    for (int j = 0; j < 4; ++j)
      w[j] = *(const float4*)&Wl[(o0 + j) * CTOT + (cc ^ wsw)];
#pragma unroll
    for (int i = 0; i < 4; ++i)
#pragma unroll
      for (int j = 0; j < 4; ++j)
        acc[i][j] += f[i].x * w[j].x + f[i].y * w[j].y + f[i].z * w[j].z +
                     f[i].w * w[j].w;
  }

#pragma unroll
  for (int i = 0; i < 4; ++i) {
    *(float4*)(hout + (size_t)(R0 + r0 + i) * COUT + o0) =
        make_float4(acc[i][0], acc[i][1], acc[i][2], acc[i][3]);
  }

  __syncthreads();
  float* red = Fl;
#pragma unroll
  for (int j = 0; j < 4; ++j) {
    float s = acc[0][j] + acc[1][j] + acc[2][j] + acc[3][j];
    float qq = acc[0][j] * acc[0][j] + acc[1][j] * acc[1][j] +
               acc[2][j] * acc[2][j] + acc[3][j] * acc[3][j];
    red[(o0 + j) * 16 + rg] = s;
    red[1024 + (o0 + j) * 16 + rg] = qq;
  }
  __syncthreads();
  if (t < 128) {
    int o = t & 63, which = t >> 6;
    const float* b = red + which * 1024 + o * 16;
    float v = 0.f;
#pragma unroll
    for (int k = 0; k < 16; ++k) v += b[k];
    atomicAdd(stats + which * COUT + o, v);
  }
}

// ---------------------------------------------------------------------------
__global__ __launch_bounds__(256) void bn_apply_kernel(
    float* __restrict__ hout, const float* __restrict__ stats,
    const float* __restrict__ gamma, const float* __restrict__ beta) {
  const int i4 = blockIdx.x * 256 + threadIdx.x;
  const int oi = i4 & 15;
  float4 h = ((const float4*)hout)[i4];
  const float4 s = ((const float4*)stats)[oi];
  const float4 q = ((const float4*)(stats + COUT))[oi];
  const float4 g = ((const float4*)gamma)[oi];
  const float4 bb = ((const float4*)beta)[oi];
  const float inv = 1.f / 16384.f;
  float m, vv, rs;
  m = s.x * inv; vv = q.x * inv - m * m; rs = rsqrtf(vv + 1e-5f);
  h.x = (h.x - m) * rs * g.x + bb.x;
  m = s.y * inv; vv = q.y * inv - m * m; rs = rsqrtf(vv + 1e-5f);
  h.y = (h.y - m) * rs * g.y + bb.y;
  m = s.z * inv; vv = q.z * inv - m * m; rs = rsqrtf(vv + 1e-5f);
  h.z = (h.z - m) * rs * g.z + bb.z;
  m = s.w * inv; vv = q.w * inv - m * m; rs = rsqrtf(vv + 1e-5f);
  h.w = (h.w - m) * rs * g.w + bb.w;
  ((float4*)hout)[i4] = h;
}

// ---------------------------------------------------------------------------
extern "C" void kernel_launch(void* const* d_in, const int* in_sizes, int n_in,
                              void* d_out, int out_size, void* d_ws,
                              size_t ws_size, hipStream_t stream) {
  const float* x     = (const float*)d_in[0];
  const float* A0    = (const float*)d_in[1];
  const float* A1    = (const float*)d_in[2];
  const float* A2    = (const float*)d_in[3];
  const float* W     = (const float*)d_in[4];
  const float* b     = (const float*)d_in[5];
  const float* gamma = (const float*)d_in[6];
  const float* beta  = (const float*)d_in[7];
  float* out = (float*)d_out;

  char* ws = (char*)d_ws;
  float* stats = (float*)ws;
  const size_t BUF = (size_t)NB * V * CIN;  // 524288 floats (2 MB)
  float* x1_0 = (float*)(ws + 4096);
  float* x2_0 = x1_0 + BUF;
  float* x1_1 = x2_0 + BUF;
  float* x2_1 = x1_1 + BUF;
  float* x1_2 = x2_1 + BUF;
  float* x2_2 = x1_2 + BUF;

  hipMemsetAsync(stats, 0, 2 * COUT * sizeof(float), stream);

  dim3 g(512), blk(256);
  nconv_mfma_kernel<<<g, blk, 0, stream>>>(A0, x, x1_0);
  nconv_mfma_kernel<<<g, blk, 0, stream>>>(A0, x1_0, x2_0);
  nconv_mfma_kernel<<<g, blk, 0, stream>>>(A1, x, x1_1);
  nconv_mfma_kernel<<<g, blk, 0, stream>>>(A1, x1_1, x2_1);
  nconv_mfma_kernel<<<g, blk, 0, stream>>>(A2, x, x1_2);
  nconv_mfma_kernel<<<g, blk, 0, stream>>>(A2, x1_2, x2_2);

  conv_bn_stats_kernel<<<dim3(256), blk, 0, stream>>>(
      W, b, x, x1_0, x2_0, x1_1, x2_1, x1_2, x2_2, out, stats);
  bn_apply_kernel<<<dim3(1024), blk, 0, stream>>>(out, stats, gamma, beta);
}